// Round 1
// baseline (1096.644 us; speedup 1.0000x reference)
//
#include <hip/hip_runtime.h>
#include <cstdint>
#include <cstddef>

#define NPIX (512 * 512)
#define NMAPS 64
#define NPTS 300
#define CAP 4096
#define NWORDS 4096  // 262144 bits / 64

// ---------------------------------------------------------------------------
// Threefry-2x32, 20 rounds (exactly JAX's formulation).
// ---------------------------------------------------------------------------
__device__ __forceinline__ void tf2x32(uint32_t k0, uint32_t k1,
                                       uint32_t x0, uint32_t x1,
                                       uint32_t& o0, uint32_t& o1) {
  uint32_t ks2 = k0 ^ k1 ^ 0x1BD11BDAu;
#define TFR(r) { x0 += x1; x1 = (x1 << (r)) | (x1 >> (32 - (r))); x1 ^= x0; }
  x0 += k0; x1 += k1;
  TFR(13) TFR(15) TFR(26) TFR(6)
  x0 += k1; x1 += ks2 + 1u;
  TFR(17) TFR(29) TFR(16) TFR(24)
  x0 += ks2; x1 += k0 + 2u;
  TFR(13) TFR(15) TFR(26) TFR(6)
  x0 += k0; x1 += k1 + 3u;
  TFR(17) TFR(29) TFR(16) TFR(24)
  x0 += k1; x1 += ks2 + 4u;
  TFR(13) TFR(15) TFR(26) TFR(6)
  x0 += ks2; x1 += k0 + 5u;
#undef TFR
  o0 = x0; o1 = x1;
}

// jax_threefry_partitionable=True (default since jax 0.4.30):
//   split(key, n)[i]  = full block of counter (hi=0, lo=i)
//   random_bits 32-bit at flat index p = o0 ^ o1 of block (0, p)
// uniform float32 keeps mantissa bits>>9 (monotone) — compare as 23-bit int.
__device__ __forceinline__ uint32_t score23(uint32_t k0, uint32_t k1, uint32_t p) {
  uint32_t a, b;
  tf2x32(k0, k1, 0u, p, a, b);
  return (a ^ b) >> 9;
}

__device__ __forceinline__ void map_key(int m, uint32_t& k0, uint32_t& k1) {
  // key(42) == (0, 42); map m uses split(key,64)[m]
  tf2x32(0u, 42u, 0u, (uint32_t)m, k0, k1);
}

// ---------------------------------------------------------------------------
// K1: edge magnitude (Sobel w/ zero pad; sigmoid for pred maps) -> bitmask
// map m: b = m>>1, which = m&1 (0 = sigmoid(model_output), 1 = labels)
// ---------------------------------------------------------------------------
__global__ void edge_mask_kernel(const float* __restrict__ mo,
                                 const float* __restrict__ lb,
                                 unsigned long long* __restrict__ bitmap,
                                 unsigned int* __restrict__ counts) {
  const int m = blockIdx.y;
  const int b = m >> 1;
  const int which = m & 1;
  const float* __restrict__ src = (which ? lb : mo) + (size_t)b * NPIX;
  const int flat = blockIdx.x * blockDim.x + threadIdx.x;
  const int y = flat >> 9;
  const int x = flat & 511;

  float v[3][3];
#pragma unroll
  for (int dy = 0; dy < 3; ++dy) {
#pragma unroll
    for (int dx = 0; dx < 3; ++dx) {
      int yy = y + dy - 1, xx = x + dx - 1;
      float t = 0.f;
      if (yy >= 0 && yy < 512 && xx >= 0 && xx < 512) {
        t = src[yy * 512 + xx];
        if (!which) t = 1.f / (1.f + expf(-t));  // sigmoid, pad applied AFTER
      }
      v[dy][dx] = t;
    }
  }
  float ex = (v[0][2] - v[0][0]) + 2.f * (v[1][2] - v[1][0]) + (v[2][2] - v[2][0]);
  float ey = (v[2][0] + 2.f * v[2][1] + v[2][2]) - (v[0][0] + 2.f * v[0][1] + v[0][2]);
  float edge = sqrtf(ex * ex + ey * ey);
  bool bit = edge > 0.5f;

  unsigned long long ball = __ballot(bit);
  __shared__ unsigned int blk;
  if (threadIdx.x == 0) blk = 0;
  __syncthreads();
  if ((threadIdx.x & 63) == 0) {
    bitmap[(size_t)m * NWORDS + (flat >> 6)] = ball;
    if (ball) atomicAdd(&blk, (unsigned int)__popcll(ball));
  }
  __syncthreads();
  if (threadIdx.x == 0 && blk) atomicAdd(&counts[m], blk);
}

// ---------------------------------------------------------------------------
// K2: exact top-300 per map. Quantile threshold on 23-bit scores; a count
// pass verifies >= min(300, N) survivors (=> survivors contain the true
// top-300). Survivors (~1200 expected) collected to LDS, bitonic sorted by
// (score desc, idx asc) via key (score<<32 | ~idx).
// ---------------------------------------------------------------------------
__global__ __launch_bounds__(1024) void select_kernel(
    const unsigned long long* __restrict__ bitmap,
    const unsigned int* __restrict__ counts,
    float2* __restrict__ pts,
    unsigned int* __restrict__ nsel) {
  const int m = blockIdx.x;
  const int tid = threadIdx.x;
  __shared__ unsigned long long buf[CAP];
  __shared__ unsigned int tot;
  __shared__ unsigned int scnt;

  uint32_t k0, k1;
  map_key(m, k0, k1);

  const unsigned int N = counts[m];
  if (N == 0) { if (tid == 0) nsel[m] = 0; return; }
  const unsigned int need = N < NPTS ? N : NPTS;
  const unsigned long long* __restrict__ wmap = bitmap + (size_t)m * NWORDS;

  unsigned int mt = 0;
  double target = 1200.0;
  unsigned int cnt = 0;
  for (int iter = 0; iter < 12; ++iter) {
    mt = ((double)N > target)
             ? (unsigned int)(8388608.0 * (1.0 - target / (double)N))
             : 0u;
    if (tid == 0) tot = 0;
    __syncthreads();
    unsigned int lc = 0;
    for (int w = tid; w < NWORDS; w += 1024) {
      unsigned long long word = wmap[w];
      while (word) {
        int bpos = __builtin_ctzll(word);
        word &= word - 1;
        uint32_t p = ((uint32_t)w << 6) + (uint32_t)bpos;
        lc += (score23(k0, k1, p) >= mt) ? 1u : 0u;
      }
    }
    if (lc) atomicAdd(&tot, lc);
    __syncthreads();
    cnt = tot;
    __syncthreads();
    if (cnt >= need && cnt <= CAP) break;
    if (cnt < need) target *= 4.0; else target *= 0.5;
  }

  // collect survivors
  if (tid == 0) scnt = 0;
  __syncthreads();
  for (int w = tid; w < NWORDS; w += 1024) {
    unsigned long long word = wmap[w];
    while (word) {
      int bpos = __builtin_ctzll(word);
      word &= word - 1;
      uint32_t p = ((uint32_t)w << 6) + (uint32_t)bpos;
      uint32_t sc = score23(k0, k1, p);
      if (sc >= mt) {
        unsigned int pos = atomicAdd(&scnt, 1u);
        if (pos < CAP)
          buf[pos] = ((unsigned long long)sc << 32) | (uint32_t)(~p);
      }
    }
  }
  __syncthreads();
  unsigned int c = scnt < CAP ? scnt : CAP;
  unsigned int P = 1;
  while (P < c) P <<= 1;
  for (unsigned int i = c + tid; i < P; i += 1024) buf[i] = 0ull;
  __syncthreads();

  // bitonic sort descending
  for (unsigned int k = 2; k <= P; k <<= 1) {
    for (unsigned int j = k >> 1; j > 0; j >>= 1) {
      for (unsigned int i = tid; i < P; i += 1024) {
        unsigned int l = i ^ j;
        if (l > i) {
          unsigned long long a = buf[i], bb = buf[l];
          bool desc = ((i & k) == 0);
          if (desc ? (a < bb) : (a > bb)) { buf[i] = bb; buf[l] = a; }
        }
      }
      __syncthreads();
    }
  }

  unsigned int n = c < NPTS ? c : NPTS;
  for (unsigned int i = tid; i < n; i += 1024) {
    uint32_t p = ~(uint32_t)buf[i];
    pts[(size_t)m * NPTS + i] =
        make_float2((float)(p >> 9), (float)(p & 511u));  // (row, col)
  }
  if (tid == 0) nsel[m] = n;
}

// ---------------------------------------------------------------------------
// K3: Prim MST over n<=300 points, sum of squared edge lengths.
// (Pad duplicates in the reference contribute zero-length edges, so MST over
//  the n distinct selected points is exactly equivalent. MST edge-weight
//  multiset is unique even with ties, so argmin tie-breaking is irrelevant.)
// ---------------------------------------------------------------------------
__global__ __launch_bounds__(320) void mst_kernel(
    const float2* __restrict__ pts,
    const unsigned int* __restrict__ nsel,
    float* __restrict__ tps) {
  const int m = blockIdx.x;
  const int tid = threadIdx.x;
  const int n = (int)nsel[m];
  __shared__ float2 sp[NPTS];
  __shared__ unsigned long long wred[5];
  __shared__ unsigned long long sbest;
  if (n <= 1) { if (tid == 0) tps[m] = 0.f; return; }
  if (tid < n) sp[tid] = pts[(size_t)m * NPTS + tid];
  __syncthreads();
  float px = 0.f, py = 0.f;
  if (tid < n) { px = sp[tid].x; py = sp[tid].y; }
  bool intree = (tid == 0);
  float mind = __int_as_float(0x7f800000);  // +inf
  if (tid > 0 && tid < n) {
    float dx = px - sp[0].x, dy = py - sp[0].y;
    mind = sqrtf(dx * dx + dy * dy);
  }
  float tp = 0.f;
  for (int it = 0; it < n - 1; ++it) {
    unsigned long long cand =
        (tid < n && !intree)
            ? (((unsigned long long)__float_as_uint(mind) << 32) |
               (unsigned int)tid)
            : ~0ull;
#pragma unroll
    for (int off = 32; off > 0; off >>= 1) {
      unsigned long long o = __shfl_xor(cand, off, 64);
      cand = o < cand ? o : cand;
    }
    if ((tid & 63) == 0) wred[tid >> 6] = cand;
    __syncthreads();
    if (tid == 0) {
      unsigned long long bb = wred[0];
#pragma unroll
      for (int i = 1; i < 5; ++i) bb = wred[i] < bb ? wred[i] : bb;
      sbest = bb;
      float wv = __uint_as_float((uint32_t)(bb >> 32));
      tp += wv * wv;
    }
    __syncthreads();
    unsigned long long bb = sbest;
    int j = (int)(uint32_t)bb;
    if (tid == j) intree = true;
    if (tid < n && !intree) {
      float dx = px - sp[j].x, dy = py - sp[j].y;
      float d = sqrtf(dx * dx + dy * dy);
      mind = d < mind ? d : mind;
    }
    __syncthreads();
  }
  if (tid == 0) tps[m] = tp;
}

// ---------------------------------------------------------------------------
// K4: loss = LAM * sum_b |tp_mask - tp_pred| / B
// ---------------------------------------------------------------------------
__global__ void finalize_kernel(const float* __restrict__ tps,
                                float* __restrict__ out) {
  const int tid = threadIdx.x;
  float v = 0.f;
  if (tid < 32) v = fabsf(tps[2 * tid + 1] - tps[2 * tid]);
#pragma unroll
  for (int off = 32; off > 0; off >>= 1) v += __shfl_xor(v, off, 64);
  if (tid == 0) out[0] = 1e-5f * v / 32.f;
}

// ---------------------------------------------------------------------------
extern "C" void kernel_launch(void* const* d_in, const int* in_sizes, int n_in,
                              void* d_out, int out_size, void* d_ws,
                              size_t ws_size, hipStream_t stream) {
  const float* mo = (const float*)d_in[0];
  const float* lb = (const float*)d_in[1];
  float* out = (float*)d_out;
  char* ws = (char*)d_ws;

  // ws layout (needs ~2.26 MB):
  unsigned long long* bitmap = (unsigned long long*)ws;          // 2 MB
  unsigned int* counts = (unsigned int*)(ws + 2097152);          // 256 B
  unsigned int* nsel = (unsigned int*)(ws + 2097152 + 256);      // 256 B
  float* tps = (float*)(ws + 2097152 + 512);                     // 256 B
  float2* pts = (float2*)(ws + 2097152 + 1024);                  // 150 KB

  hipMemsetAsync(counts, 0, 256, stream);
  edge_mask_kernel<<<dim3(NPIX / 256, NMAPS), 256, 0, stream>>>(mo, lb, bitmap,
                                                                counts);
  select_kernel<<<NMAPS, 1024, 0, stream>>>(bitmap, counts, pts, nsel);
  mst_kernel<<<NMAPS, 320, 0, stream>>>(pts, nsel, tps);
  finalize_kernel<<<1, 64, 0, stream>>>(tps, out);
}

// Round 2
// 859.143 us; speedup vs baseline: 1.2764x; 1.2764x over previous
//
#include <hip/hip_runtime.h>
#include <cstdint>
#include <cstddef>

#define NPIX (512 * 512)
#define NMAPS 64
#define NPTS 300
#define CAP 2048          // global candidate cap per map (mean ~700)
#define LCAP 640          // per-block LDS candidate cap (mean ~44)
#define NWORDS 4096       // 262144 bits / 64
#define TARGET 700.0      // expected survivor count per map

// ---------------------------------------------------------------------------
// Threefry-2x32, 20 rounds (exactly JAX's formulation).
// ---------------------------------------------------------------------------
__device__ __forceinline__ void tf2x32(uint32_t k0, uint32_t k1,
                                       uint32_t x0, uint32_t x1,
                                       uint32_t& o0, uint32_t& o1) {
  uint32_t ks2 = k0 ^ k1 ^ 0x1BD11BDAu;
#define TFR(r) { x0 += x1; x1 = (x1 << (r)) | (x1 >> (32 - (r))); x1 ^= x0; }
  x0 += k0; x1 += k1;
  TFR(13) TFR(15) TFR(26) TFR(6)
  x0 += k1; x1 += ks2 + 1u;
  TFR(17) TFR(29) TFR(16) TFR(24)
  x0 += ks2; x1 += k0 + 2u;
  TFR(13) TFR(15) TFR(26) TFR(6)
  x0 += k0; x1 += k1 + 3u;
  TFR(17) TFR(29) TFR(16) TFR(24)
  x0 += k1; x1 += ks2 + 4u;
  TFR(13) TFR(15) TFR(26) TFR(6)
  x0 += ks2; x1 += k0 + 5u;
#undef TFR
  o0 = x0; o1 = x1;
}

// partitionable threefry: bits at flat pixel p = o0^o1 of block (0,p);
// uniform f32 keeps mantissa bits>>9 (monotone) — compare as 23-bit ints.
__device__ __forceinline__ uint32_t score23(uint32_t k0, uint32_t k1, uint32_t p) {
  uint32_t a, b;
  tf2x32(k0, k1, 0u, p, a, b);
  return (a ^ b) >> 9;
}

__device__ __forceinline__ void map_key(int m, uint32_t& k0, uint32_t& k1) {
  tf2x32(0u, 42u, 0u, (uint32_t)m, k0, k1);  // split(key(42),64)[m]
}

__device__ __forceinline__ uint32_t thr_from_N(unsigned int N) {
  return ((double)N > TARGET)
             ? (uint32_t)(8388608.0 * (1.0 - TARGET / (double)N))
             : 0u;
}

// ---------------------------------------------------------------------------
// K1: LDS-tiled Sobel (sigmoid for pred maps applied ONCE per staged value,
// zero-pad AFTER sigmoid as in the reference). Tile 64x4 + halo -> 66x6.
// One wave = one row of 64 px -> ballot is the bitmap word directly.
// ---------------------------------------------------------------------------
__global__ __launch_bounds__(256) void edge_mask_kernel(
    const float* __restrict__ mo, const float* __restrict__ lb,
    unsigned long long* __restrict__ bitmap, unsigned int* __restrict__ counts) {
  const int m = blockIdx.z;
  const int b = m >> 1;
  const int which = m & 1;
  const float* __restrict__ src = (which ? lb : mo) + (size_t)b * NPIX;
  const int tileX = blockIdx.x * 64;
  const int tileY = blockIdx.y * 4;
  const int tid = threadIdx.x;

  __shared__ float s[6][66];
  __shared__ unsigned int blk;
  if (tid == 0) blk = 0;

  for (int i = tid; i < 396; i += 256) {
    int ly = i / 66;
    int lx = i - ly * 66;
    int gy = tileY + ly - 1;
    int gx = tileX + lx - 1;
    float t = 0.f;
    if (gy >= 0 && gy < 512 && gx >= 0 && gx < 512) {
      t = src[gy * 512 + gx];
      if (!which) t = 1.f / (1.f + expf(-t));
    }
    s[ly][lx] = t;
  }
  __syncthreads();

  const int tx = tid & 63;
  const int ty = tid >> 6;
  float v00 = s[ty][tx],     v01 = s[ty][tx + 1],     v02 = s[ty][tx + 2];
  float v10 = s[ty + 1][tx],                          v12 = s[ty + 1][tx + 2];
  float v20 = s[ty + 2][tx], v21 = s[ty + 2][tx + 1], v22 = s[ty + 2][tx + 2];
  float ex = (v02 - v00) + 2.f * (v12 - v10) + (v22 - v20);
  float ey = (v20 + 2.f * v21 + v22) - (v00 + 2.f * v01 + v02);
  float edge = sqrtf(ex * ex + ey * ey);
  bool bit = edge > 0.5f;

  unsigned long long ball = __ballot(bit);
  if (tx == 0) {
    bitmap[(size_t)m * NWORDS + (size_t)(tileY + ty) * 8 + blockIdx.x] = ball;
    if (ball) atomicAdd(&blk, (unsigned int)__popcll(ball));
  }
  __syncthreads();
  if (tid == 0 && blk) atomicAdd(&counts[m], blk);
}

// ---------------------------------------------------------------------------
// K2a: grid-wide candidate collection. One thread per 64-bit bitmap word;
// threefry per set bit; survivors (score >= mt) appended to per-block LDS,
// flushed with ONE global atomic per block. Overflow poisons gcnt -> K2b
// falls back to an exact rescan.
// ---------------------------------------------------------------------------
__global__ __launch_bounds__(256) void collect_kernel(
    const unsigned long long* __restrict__ bitmap,
    const unsigned int* __restrict__ counts,
    unsigned long long* __restrict__ cand, unsigned int* __restrict__ gcnt) {
  const int m = blockIdx.y;
  const int tid = threadIdx.x;
  const int w = blockIdx.x * 256 + tid;

  __shared__ unsigned long long lbuf[LCAP];
  __shared__ unsigned int lcnt;
  __shared__ unsigned int lbase;
  if (tid == 0) lcnt = 0;
  __syncthreads();

  const unsigned int N = counts[m];
  if (N) {
    const uint32_t mt = thr_from_N(N);
    uint32_t k0, k1;
    map_key(m, k0, k1);
    unsigned long long word = bitmap[(size_t)m * NWORDS + w];
    while (word) {
      int bpos = __builtin_ctzll(word);
      word &= word - 1;
      uint32_t p = ((uint32_t)w << 6) + (uint32_t)bpos;
      uint32_t sc = score23(k0, k1, p);
      if (sc >= mt) {
        unsigned int pos = atomicAdd(&lcnt, 1u);
        if (pos < LCAP)
          lbuf[pos] = ((unsigned long long)sc << 32) | (uint32_t)(~p);
      }
    }
  }
  __syncthreads();
  unsigned int c = lcnt < LCAP ? lcnt : LCAP;
  if (tid == 0)
    lbase = atomicAdd(&gcnt[m], lcnt + (lcnt > LCAP ? 0x1000000u : 0u));
  __syncthreads();
  for (unsigned int i = tid; i < c; i += 256) {
    unsigned int pos = lbase + i;
    if (pos < CAP) cand[(size_t)m * CAP + pos] = lbuf[i];
  }
}

// ---------------------------------------------------------------------------
// K2b: per-map bitonic sort of candidates by (score desc, idx asc), emit
// top min(c,300) points. Fallback exact rescan if collection overflowed or
// came up short (probability ~0, but deterministic safety).
// ---------------------------------------------------------------------------
__global__ __launch_bounds__(1024) void sort_kernel(
    const unsigned long long* __restrict__ bitmap,
    const unsigned int* __restrict__ counts,
    const unsigned long long* __restrict__ cand,
    const unsigned int* __restrict__ gcnt,
    float2* __restrict__ pts, unsigned int* __restrict__ nsel) {
  const int m = blockIdx.x;
  const int tid = threadIdx.x;
  __shared__ unsigned long long buf[CAP];
  __shared__ unsigned int tot;
  __shared__ unsigned int scnt;

  const unsigned int N = counts[m];
  if (N == 0) { if (tid == 0) nsel[m] = 0; return; }
  const unsigned int need = N < NPTS ? N : NPTS;

  unsigned int c;
  const unsigned int g = gcnt[m];
  if (g >= need && g <= CAP) {
    c = g;
    for (unsigned int i = tid; i < c; i += 1024)
      buf[i] = cand[(size_t)m * CAP + i];
    __syncthreads();
  } else {
    // fallback: exact iterative rescan of the bitmap
    uint32_t k0, k1;
    map_key(m, k0, k1);
    const unsigned long long* __restrict__ wmap = bitmap + (size_t)m * NWORDS;
    unsigned int mt = 0, cnt = 0;
    double target = TARGET;
    for (int iter = 0; iter < 16; ++iter) {
      mt = ((double)N > target)
               ? (unsigned int)(8388608.0 * (1.0 - target / (double)N))
               : 0u;
      if (tid == 0) tot = 0;
      __syncthreads();
      unsigned int lc = 0;
      for (int w = tid; w < NWORDS; w += 1024) {
        unsigned long long word = wmap[w];
        while (word) {
          int bpos = __builtin_ctzll(word);
          word &= word - 1;
          uint32_t p = ((uint32_t)w << 6) + (uint32_t)bpos;
          lc += (score23(k0, k1, p) >= mt) ? 1u : 0u;
        }
      }
      if (lc) atomicAdd(&tot, lc);
      __syncthreads();
      cnt = tot;
      __syncthreads();
      if (cnt >= need && cnt <= CAP) break;
      if (cnt < need) target *= 3.0; else target *= 0.5;
    }
    if (tid == 0) scnt = 0;
    __syncthreads();
    for (int w = tid; w < NWORDS; w += 1024) {
      unsigned long long word = wmap[w];
      while (word) {
        int bpos = __builtin_ctzll(word);
        word &= word - 1;
        uint32_t p = ((uint32_t)w << 6) + (uint32_t)bpos;
        uint32_t sc = score23(k0, k1, p);
        if (sc >= mt) {
          unsigned int pos = atomicAdd(&scnt, 1u);
          if (pos < CAP)
            buf[pos] = ((unsigned long long)sc << 32) | (uint32_t)(~p);
        }
      }
    }
    __syncthreads();
    c = scnt < CAP ? scnt : CAP;
  }

  unsigned int P = 1;
  while (P < c) P <<= 1;
  for (unsigned int i = c + tid; i < P; i += 1024) buf[i] = 0ull;
  __syncthreads();

  for (unsigned int k = 2; k <= P; k <<= 1) {
    for (unsigned int j = k >> 1; j > 0; j >>= 1) {
      for (unsigned int i = tid; i < P; i += 1024) {
        unsigned int l = i ^ j;
        if (l > i) {
          unsigned long long a = buf[i], bb = buf[l];
          bool desc = ((i & k) == 0);
          if (desc ? (a < bb) : (a > bb)) { buf[i] = bb; buf[l] = a; }
        }
      }
      __syncthreads();
    }
  }

  unsigned int n = c < NPTS ? c : NPTS;
  for (unsigned int i = tid; i < n; i += 1024) {
    uint32_t p = ~(uint32_t)buf[i];
    pts[(size_t)m * NPTS + i] =
        make_float2((float)(p >> 9), (float)(p & 511u));  // (row, col)
  }
  if (tid == 0) nsel[m] = n;
}

// ---------------------------------------------------------------------------
// K3: Prim MST, ONE wave per map, 5 points/lane, shfl-only reduction (zero
// barriers in the main loop). Tracks min squared distance (monotone with
// distance -> same MST edge multiset; sum(d2) vs sum(fl(sqrt(d2))^2) differs
// by ulps, far under tolerance).
// ---------------------------------------------------------------------------
__global__ __launch_bounds__(64) void mst_kernel(
    const float2* __restrict__ pts, const unsigned int* __restrict__ nsel,
    float* __restrict__ tps) {
  const int m = blockIdx.x;
  const int l = threadIdx.x;
  const int n = (int)nsel[m];
  __shared__ float spx[NPTS], spy[NPTS];
  if (n <= 1) { if (l == 0) tps[m] = 0.f; return; }

  const float INF = __int_as_float(0x7f800000);
  float px[5], py[5], md[5];
#pragma unroll
  for (int k = 0; k < 5; ++k) {
    int id = k * 64 + l;
    px[k] = 0.f; py[k] = 0.f; md[k] = INF;
    if (id < n) {
      float2 p = pts[(size_t)m * NPTS + id];
      px[k] = p.x; py[k] = p.y;
      spx[id] = p.x; spy[id] = p.y;
    }
  }
  __syncthreads();
  const float x0 = spx[0], y0 = spy[0];
  int tmask = (l == 0) ? 1 : 0;
#pragma unroll
  for (int k = 0; k < 5; ++k) {
    int id = k * 64 + l;
    if (id > 0 && id < n) {
      float dx = px[k] - x0, dy = py[k] - y0;
      md[k] = dx * dx + dy * dy;
    }
  }

  float tp = 0.f;
  for (int it = 0; it < n - 1; ++it) {
    unsigned long long best = ~0ull;
#pragma unroll
    for (int k = 0; k < 5; ++k) {
      int id = k * 64 + l;
      if (!((tmask >> k) & 1) && id < n) {
        unsigned long long key =
            ((unsigned long long)__float_as_uint(md[k]) << 32) |
            (unsigned int)id;
        best = key < best ? key : best;
      }
    }
#pragma unroll
    for (int off = 32; off > 0; off >>= 1) {
      unsigned long long o = __shfl_xor(best, off, 64);
      best = o < best ? o : best;
    }
    float w2 = __uint_as_float((uint32_t)(best >> 32));
    int j = (int)(uint32_t)best;
    tp += w2;
    if ((j & 63) == l) tmask |= 1 << (j >> 6);
    float jx = spx[j], jy = spy[j];
#pragma unroll
    for (int k = 0; k < 5; ++k) {
      float dx = px[k] - jx, dy = py[k] - jy;
      float d2 = dx * dx + dy * dy;
      md[k] = d2 < md[k] ? d2 : md[k];
    }
  }
  if (l == 0) tps[m] = tp;
}

// ---------------------------------------------------------------------------
// K4: loss = 1e-5 * sum_b |tp_mask - tp_pred| / 32
// ---------------------------------------------------------------------------
__global__ void finalize_kernel(const float* __restrict__ tps,
                                float* __restrict__ out) {
  const int tid = threadIdx.x;
  float v = 0.f;
  if (tid < 32) v = fabsf(tps[2 * tid + 1] - tps[2 * tid]);
#pragma unroll
  for (int off = 32; off > 0; off >>= 1) v += __shfl_xor(v, off, 64);
  if (tid == 0) out[0] = 1e-5f * v / 32.f;
}

// ---------------------------------------------------------------------------
extern "C" void kernel_launch(void* const* d_in, const int* in_sizes, int n_in,
                              void* d_out, int out_size, void* d_ws,
                              size_t ws_size, hipStream_t stream) {
  const float* mo = (const float*)d_in[0];
  const float* lb = (const float*)d_in[1];
  float* out = (float*)d_out;
  char* ws = (char*)d_ws;

  // ws layout (~3.2 MB):
  unsigned long long* bitmap = (unsigned long long*)ws;            // 2 MB
  unsigned int* counts = (unsigned int*)(ws + 2097152);            // 256 B
  unsigned int* gcnt   = (unsigned int*)(ws + 2097408);            // 256 B
  unsigned int* nsel   = (unsigned int*)(ws + 2097664);            // 256 B
  float* tps           = (float*)(ws + 2097920);                   // 256 B
  float2* pts          = (float2*)(ws + 2098176);                  // 150 KB
  unsigned long long* cand = (unsigned long long*)(ws + 2251776);  // 1 MB

  hipMemsetAsync(counts, 0, 512, stream);  // counts + gcnt
  edge_mask_kernel<<<dim3(8, 128, 64), 256, 0, stream>>>(mo, lb, bitmap, counts);
  collect_kernel<<<dim3(16, 64), 256, 0, stream>>>(bitmap, counts, cand, gcnt);
  sort_kernel<<<NMAPS, 1024, 0, stream>>>(bitmap, counts, cand, gcnt, pts, nsel);
  mst_kernel<<<NMAPS, 64, 0, stream>>>(pts, nsel, tps);
  finalize_kernel<<<1, 64, 0, stream>>>(tps, out);
}

// Round 3
// 349.216 us; speedup vs baseline: 3.1403x; 2.4602x over previous
//
#include <hip/hip_runtime.h>
#include <cstdint>
#include <cstddef>

#define NPIX (512 * 512)
#define NMAPS 64
#define NPTS 300
#define CAP 2048          // global candidate cap per map (mean ~700)
#define LCAP 640          // per-block LDS candidate cap (mean ~44)
#define NWORDS 4096       // 262144 bits / 64
#define TARGET 700.0      // expected survivor count per map

// ---------------------------------------------------------------------------
// Threefry-2x32, 20 rounds (exactly JAX's formulation).
// ---------------------------------------------------------------------------
__device__ __forceinline__ void tf2x32(uint32_t k0, uint32_t k1,
                                       uint32_t x0, uint32_t x1,
                                       uint32_t& o0, uint32_t& o1) {
  uint32_t ks2 = k0 ^ k1 ^ 0x1BD11BDAu;
#define TFR(r) { x0 += x1; x1 = (x1 << (r)) | (x1 >> (32 - (r))); x1 ^= x0; }
  x0 += k0; x1 += k1;
  TFR(13) TFR(15) TFR(26) TFR(6)
  x0 += k1; x1 += ks2 + 1u;
  TFR(17) TFR(29) TFR(16) TFR(24)
  x0 += ks2; x1 += k0 + 2u;
  TFR(13) TFR(15) TFR(26) TFR(6)
  x0 += k0; x1 += k1 + 3u;
  TFR(17) TFR(29) TFR(16) TFR(24)
  x0 += k1; x1 += ks2 + 4u;
  TFR(13) TFR(15) TFR(26) TFR(6)
  x0 += ks2; x1 += k0 + 5u;
#undef TFR
  o0 = x0; o1 = x1;
}

// partitionable threefry: bits at flat pixel p = o0^o1 of block (0,p);
// uniform f32 keeps mantissa bits>>9 (monotone) — compare as 23-bit ints.
__device__ __forceinline__ uint32_t score23(uint32_t k0, uint32_t k1, uint32_t p) {
  uint32_t a, b;
  tf2x32(k0, k1, 0u, p, a, b);
  return (a ^ b) >> 9;
}

__device__ __forceinline__ void map_key(int m, uint32_t& k0, uint32_t& k1) {
  tf2x32(0u, 42u, 0u, (uint32_t)m, k0, k1);  // split(key(42),64)[m]
}

__device__ __forceinline__ uint32_t thr_from_N(unsigned int N) {
  return ((double)N > TARGET)
             ? (uint32_t)(8388608.0 * (1.0 - TARGET / (double)N))
             : 0u;
}

// ---------------------------------------------------------------------------
// K1: wave-rolling Sobel. One wave owns a 64-col x 32-row strip; rows roll
// through registers (1 coalesced load/row + 2-lane halo load); col neighbors
// via shfl; ballot IS the bitmap word. Zero barriers, zero LDS, one global
// atomic per wave (128/counter vs 16K/cache-line before — the round-2
// bottleneck theory). Sigmoid once per load, zero-pad AFTER sigmoid.
// ---------------------------------------------------------------------------
__global__ __launch_bounds__(256) void edge_mask_kernel(
    const float* __restrict__ mo, const float* __restrict__ lb,
    unsigned long long* __restrict__ bitmap, unsigned int* __restrict__ counts) {
  const int m = blockIdx.y;
  const int which = m & 1;
  const float* __restrict__ src = (which ? lb : mo) + (size_t)(m >> 1) * NPIX;
  const int l = threadIdx.x & 63;
  const int wi = blockIdx.x * 4 + (threadIdx.x >> 6);  // [0,128)
  const int cs = wi & 7;        // column strip: cols [cs*64, cs*64+64)
  const int seg = wi >> 3;      // row segment: rows [seg*32, seg*32+32)
  const int y0 = seg * 32;
  const int X = cs * 64 + l;
  const int hcol = (l == 0) ? X - 1 : ((l == 63) ? X + 1 : -1);

  auto sig = [&](float t) { return which ? t : 1.f / (1.f + expf(-t)); };
  auto ldmain = [&](int row) -> float {
    return ((unsigned)row < 512u) ? sig(src[row * 512 + X]) : 0.f;
  };
  auto ldhalo = [&](int row) -> float {
    return ((unsigned)row < 512u && (unsigned)hcol < 512u)
               ? sig(src[row * 512 + hcol]) : 0.f;
  };

  float a = ldmain(y0 - 1), ha = ldhalo(y0 - 1);
  float b = ldmain(y0),     hb = ldhalo(y0);
  unsigned int cnt = 0;

  for (int i = 0; i < 32; ++i) {
    const int y = y0 + i;
    float c = ldmain(y + 1), hc = ldhalo(y + 1);

    // ha holds LEFT halo in lane 0 and RIGHT halo in lane 63.
    float aL = __shfl_up(a, 1);   if (l == 0)  aL = ha;
    float aR = __shfl_down(a, 1); if (l == 63) aR = ha;
    float bL = __shfl_up(b, 1);   if (l == 0)  bL = hb;
    float bR = __shfl_down(b, 1); if (l == 63) bR = hb;
    float cL = __shfl_up(c, 1);   if (l == 0)  cL = hc;
    float cR = __shfl_down(c, 1); if (l == 63) cR = hc;

    float ex = (aR - aL) + 2.f * (bR - bL) + (cR - cL);
    float ey = (cL + 2.f * c + cR) - (aL + 2.f * a + aR);
    float edge = sqrtf(ex * ex + ey * ey);
    bool bit = edge > 0.5f;

    unsigned long long ball = __ballot(bit);
    if (l == 0) {
      bitmap[(size_t)m * NWORDS + (size_t)y * 8 + cs] = ball;
      cnt += (unsigned int)__popcll(ball);
    }
    a = b; ha = hb; b = c; hb = hc;
  }
  if (l == 0 && cnt) atomicAdd(&counts[m], cnt);
}

// ---------------------------------------------------------------------------
// K2a: grid-wide candidate collection. One thread per 64-bit bitmap word;
// threefry per set bit; survivors (score >= mt) appended to per-block LDS,
// flushed with ONE global atomic per block. Overflow poisons gcnt -> K2b
// falls back to an exact rescan.
// ---------------------------------------------------------------------------
__global__ __launch_bounds__(256) void collect_kernel(
    const unsigned long long* __restrict__ bitmap,
    const unsigned int* __restrict__ counts,
    unsigned long long* __restrict__ cand, unsigned int* __restrict__ gcnt) {
  const int m = blockIdx.y;
  const int tid = threadIdx.x;
  const int w = blockIdx.x * 256 + tid;

  __shared__ unsigned long long lbuf[LCAP];
  __shared__ unsigned int lcnt;
  __shared__ unsigned int lbase;
  if (tid == 0) lcnt = 0;
  __syncthreads();

  const unsigned int N = counts[m];
  if (N) {
    const uint32_t mt = thr_from_N(N);
    uint32_t k0, k1;
    map_key(m, k0, k1);
    unsigned long long word = bitmap[(size_t)m * NWORDS + w];
    while (word) {
      int bpos = __builtin_ctzll(word);
      word &= word - 1;
      uint32_t p = ((uint32_t)w << 6) + (uint32_t)bpos;
      uint32_t sc = score23(k0, k1, p);
      if (sc >= mt) {
        unsigned int pos = atomicAdd(&lcnt, 1u);
        if (pos < LCAP)
          lbuf[pos] = ((unsigned long long)sc << 32) | (uint32_t)(~p);
      }
    }
  }
  __syncthreads();
  unsigned int c = lcnt < LCAP ? lcnt : LCAP;
  if (tid == 0)
    lbase = atomicAdd(&gcnt[m], lcnt + (lcnt > LCAP ? 0x1000000u : 0u));
  __syncthreads();
  for (unsigned int i = tid; i < c; i += 256) {
    unsigned int pos = lbase + i;
    if (pos < CAP) cand[(size_t)m * CAP + pos] = lbuf[i];
  }
}

// ---------------------------------------------------------------------------
// K2b: per-map bitonic sort of candidates by (score desc, idx asc), emit
// top min(c,300) points. Fallback exact rescan if collection overflowed or
// came up short (probability ~0, but deterministic safety).
// ---------------------------------------------------------------------------
__global__ __launch_bounds__(1024) void sort_kernel(
    const unsigned long long* __restrict__ bitmap,
    const unsigned int* __restrict__ counts,
    const unsigned long long* __restrict__ cand,
    const unsigned int* __restrict__ gcnt,
    float2* __restrict__ pts, unsigned int* __restrict__ nsel) {
  const int m = blockIdx.x;
  const int tid = threadIdx.x;
  __shared__ unsigned long long buf[CAP];
  __shared__ unsigned int tot;
  __shared__ unsigned int scnt;

  const unsigned int N = counts[m];
  if (N == 0) { if (tid == 0) nsel[m] = 0; return; }
  const unsigned int need = N < NPTS ? N : NPTS;

  unsigned int c;
  const unsigned int g = gcnt[m];
  if (g >= need && g <= CAP) {
    c = g;
    for (unsigned int i = tid; i < c; i += 1024)
      buf[i] = cand[(size_t)m * CAP + i];
    __syncthreads();
  } else {
    // fallback: exact iterative rescan of the bitmap
    uint32_t k0, k1;
    map_key(m, k0, k1);
    const unsigned long long* __restrict__ wmap = bitmap + (size_t)m * NWORDS;
    unsigned int mt = 0, cnt = 0;
    double target = TARGET;
    for (int iter = 0; iter < 16; ++iter) {
      mt = ((double)N > target)
               ? (unsigned int)(8388608.0 * (1.0 - target / (double)N))
               : 0u;
      if (tid == 0) tot = 0;
      __syncthreads();
      unsigned int lc = 0;
      for (int w = tid; w < NWORDS; w += 1024) {
        unsigned long long word = wmap[w];
        while (word) {
          int bpos = __builtin_ctzll(word);
          word &= word - 1;
          uint32_t p = ((uint32_t)w << 6) + (uint32_t)bpos;
          lc += (score23(k0, k1, p) >= mt) ? 1u : 0u;
        }
      }
      if (lc) atomicAdd(&tot, lc);
      __syncthreads();
      cnt = tot;
      __syncthreads();
      if (cnt >= need && cnt <= CAP) break;
      if (cnt < need) target *= 3.0; else target *= 0.5;
    }
    if (tid == 0) scnt = 0;
    __syncthreads();
    for (int w = tid; w < NWORDS; w += 1024) {
      unsigned long long word = wmap[w];
      while (word) {
        int bpos = __builtin_ctzll(word);
        word &= word - 1;
        uint32_t p = ((uint32_t)w << 6) + (uint32_t)bpos;
        uint32_t sc = score23(k0, k1, p);
        if (sc >= mt) {
          unsigned int pos = atomicAdd(&scnt, 1u);
          if (pos < CAP)
            buf[pos] = ((unsigned long long)sc << 32) | (uint32_t)(~p);
        }
      }
    }
    __syncthreads();
    c = scnt < CAP ? scnt : CAP;
  }

  unsigned int P = 1;
  while (P < c) P <<= 1;
  for (unsigned int i = c + tid; i < P; i += 1024) buf[i] = 0ull;
  __syncthreads();

  for (unsigned int k = 2; k <= P; k <<= 1) {
    for (unsigned int j = k >> 1; j > 0; j >>= 1) {
      for (unsigned int i = tid; i < P; i += 1024) {
        unsigned int l = i ^ j;
        if (l > i) {
          unsigned long long a = buf[i], bb = buf[l];
          bool desc = ((i & k) == 0);
          if (desc ? (a < bb) : (a > bb)) { buf[i] = bb; buf[l] = a; }
        }
      }
      __syncthreads();
    }
  }

  unsigned int n = c < NPTS ? c : NPTS;
  for (unsigned int i = tid; i < n; i += 1024) {
    uint32_t p = ~(uint32_t)buf[i];
    pts[(size_t)m * NPTS + i] =
        make_float2((float)(p >> 9), (float)(p & 511u));  // (row, col)
  }
  if (tid == 0) nsel[m] = n;
}

// ---------------------------------------------------------------------------
// K3: Prim MST, ONE wave per map, 5 points/lane, shfl-only reduction (zero
// barriers in the main loop). Tracks min squared distance (monotone with
// distance -> same MST edge multiset; sum(d2) vs sum(fl(sqrt(d2))^2) differs
// by ulps, far under tolerance).
// ---------------------------------------------------------------------------
__global__ __launch_bounds__(64) void mst_kernel(
    const float2* __restrict__ pts, const unsigned int* __restrict__ nsel,
    float* __restrict__ tps) {
  const int m = blockIdx.x;
  const int l = threadIdx.x;
  const int n = (int)nsel[m];
  __shared__ float spx[NPTS], spy[NPTS];
  if (n <= 1) { if (l == 0) tps[m] = 0.f; return; }

  const float INF = __int_as_float(0x7f800000);
  float px[5], py[5], md[5];
#pragma unroll
  for (int k = 0; k < 5; ++k) {
    int id = k * 64 + l;
    px[k] = 0.f; py[k] = 0.f; md[k] = INF;
    if (id < n) {
      float2 p = pts[(size_t)m * NPTS + id];
      px[k] = p.x; py[k] = p.y;
      spx[id] = p.x; spy[id] = p.y;
    }
  }
  __syncthreads();
  const float x0 = spx[0], y0 = spy[0];
  int tmask = (l == 0) ? 1 : 0;
#pragma unroll
  for (int k = 0; k < 5; ++k) {
    int id = k * 64 + l;
    if (id > 0 && id < n) {
      float dx = px[k] - x0, dy = py[k] - y0;
      md[k] = dx * dx + dy * dy;
    }
  }

  float tp = 0.f;
  for (int it = 0; it < n - 1; ++it) {
    unsigned long long best = ~0ull;
#pragma unroll
    for (int k = 0; k < 5; ++k) {
      int id = k * 64 + l;
      if (!((tmask >> k) & 1) && id < n) {
        unsigned long long key =
            ((unsigned long long)__float_as_uint(md[k]) << 32) |
            (unsigned int)id;
        best = key < best ? key : best;
      }
    }
#pragma unroll
    for (int off = 32; off > 0; off >>= 1) {
      unsigned long long o = __shfl_xor(best, off, 64);
      best = o < best ? o : best;
    }
    float w2 = __uint_as_float((uint32_t)(best >> 32));
    int j = (int)(uint32_t)best;
    tp += w2;
    if ((j & 63) == l) tmask |= 1 << (j >> 6);
    float jx = spx[j], jy = spy[j];
#pragma unroll
    for (int k = 0; k < 5; ++k) {
      float dx = px[k] - jx, dy = py[k] - jy;
      float d2 = dx * dx + dy * dy;
      md[k] = d2 < md[k] ? d2 : md[k];
    }
  }
  if (l == 0) tps[m] = tp;
}

// ---------------------------------------------------------------------------
// K4: loss = 1e-5 * sum_b |tp_mask - tp_pred| / 32
// ---------------------------------------------------------------------------
__global__ void finalize_kernel(const float* __restrict__ tps,
                                float* __restrict__ out) {
  const int tid = threadIdx.x;
  float v = 0.f;
  if (tid < 32) v = fabsf(tps[2 * tid + 1] - tps[2 * tid]);
#pragma unroll
  for (int off = 32; off > 0; off >>= 1) v += __shfl_xor(v, off, 64);
  if (tid == 0) out[0] = 1e-5f * v / 32.f;
}

// ---------------------------------------------------------------------------
extern "C" void kernel_launch(void* const* d_in, const int* in_sizes, int n_in,
                              void* d_out, int out_size, void* d_ws,
                              size_t ws_size, hipStream_t stream) {
  const float* mo = (const float*)d_in[0];
  const float* lb = (const float*)d_in[1];
  float* out = (float*)d_out;
  char* ws = (char*)d_ws;

  // ws layout (~3.2 MB):
  unsigned long long* bitmap = (unsigned long long*)ws;            // 2 MB
  unsigned int* counts = (unsigned int*)(ws + 2097152);            // 256 B
  unsigned int* gcnt   = (unsigned int*)(ws + 2097408);            // 256 B
  unsigned int* nsel   = (unsigned int*)(ws + 2097664);            // 256 B
  float* tps           = (float*)(ws + 2097920);                   // 256 B
  float2* pts          = (float2*)(ws + 2098176);                  // 150 KB
  unsigned long long* cand = (unsigned long long*)(ws + 2251776);  // 1 MB

  hipMemsetAsync(counts, 0, 512, stream);  // counts + gcnt
  // 2048 blocks: 64 maps x (8 col-strips x 16 row-segments) / 4 waves/block
  edge_mask_kernel<<<dim3(32, 64), 256, 0, stream>>>(mo, lb, bitmap, counts);
  collect_kernel<<<dim3(16, 64), 256, 0, stream>>>(bitmap, counts, cand, gcnt);
  sort_kernel<<<NMAPS, 1024, 0, stream>>>(bitmap, counts, cand, gcnt, pts, nsel);
  mst_kernel<<<NMAPS, 64, 0, stream>>>(pts, nsel, tps);
  finalize_kernel<<<1, 64, 0, stream>>>(tps, out);
}

// Round 4
// 282.054 us; speedup vs baseline: 3.8881x; 1.2381x over previous
//
#include <hip/hip_runtime.h>
#include <cstdint>
#include <cstddef>

#define NPIX (512 * 512)
#define NMAPS 64
#define NPTS 300
#define CAP 2048          // global candidate cap per map (mean ~700)
#define LCAP 640          // per-block LDS candidate cap (mean ~44)
#define NWORDS 4096       // 262144 bits / 64
#define TARGET 700.0      // expected survivor count per map

__device__ __forceinline__ uint32_t umin32(uint32_t a, uint32_t b) {
  return a < b ? a : b;
}

// ---------------------------------------------------------------------------
// Threefry-2x32, 20 rounds (exactly JAX's formulation).
// ---------------------------------------------------------------------------
__device__ __forceinline__ void tf2x32(uint32_t k0, uint32_t k1,
                                       uint32_t x0, uint32_t x1,
                                       uint32_t& o0, uint32_t& o1) {
  uint32_t ks2 = k0 ^ k1 ^ 0x1BD11BDAu;
#define TFR(r) { x0 += x1; x1 = (x1 << (r)) | (x1 >> (32 - (r))); x1 ^= x0; }
  x0 += k0; x1 += k1;
  TFR(13) TFR(15) TFR(26) TFR(6)
  x0 += k1; x1 += ks2 + 1u;
  TFR(17) TFR(29) TFR(16) TFR(24)
  x0 += ks2; x1 += k0 + 2u;
  TFR(13) TFR(15) TFR(26) TFR(6)
  x0 += k0; x1 += k1 + 3u;
  TFR(17) TFR(29) TFR(16) TFR(24)
  x0 += k1; x1 += ks2 + 4u;
  TFR(13) TFR(15) TFR(26) TFR(6)
  x0 += ks2; x1 += k0 + 5u;
#undef TFR
  o0 = x0; o1 = x1;
}

// partitionable threefry: bits at flat pixel p = o0^o1 of block (0,p);
// uniform f32 keeps mantissa bits>>9 (monotone) — compare as 23-bit ints.
__device__ __forceinline__ uint32_t score23(uint32_t k0, uint32_t k1, uint32_t p) {
  uint32_t a, b;
  tf2x32(k0, k1, 0u, p, a, b);
  return (a ^ b) >> 9;
}

__device__ __forceinline__ void map_key(int m, uint32_t& k0, uint32_t& k1) {
  tf2x32(0u, 42u, 0u, (uint32_t)m, k0, k1);  // split(key(42),64)[m]
}

__device__ __forceinline__ uint32_t thr_from_N(unsigned int N) {
  return ((double)N > TARGET)
             ? (uint32_t)(8388608.0 * (1.0 - TARGET / (double)N))
             : 0u;
}

// ---------------------------------------------------------------------------
// DPP wave-64 min reduction (AMD GCN reduction sequence: 4x row_shr +
// row_bcast15 + row_bcast31, result in lane 63) then scalar broadcast.
// old = v everywhere => invalid/masked fetches act as min-identity.
// ---------------------------------------------------------------------------
__device__ __forceinline__ uint32_t wave_min_bcast(uint32_t v) {
#define DPPMIN(ctrl)                                                         \
  v = umin32(v, (uint32_t)__builtin_amdgcn_update_dpp(                       \
                    (int)v, (int)v, (ctrl), 0xF, 0xF, false));
  DPPMIN(0x111)  // row_shr:1
  DPPMIN(0x112)  // row_shr:2
  DPPMIN(0x114)  // row_shr:4
  DPPMIN(0x118)  // row_shr:8
  DPPMIN(0x142)  // row_bcast:15
  DPPMIN(0x143)  // row_bcast:31
#undef DPPMIN
  return (uint32_t)__builtin_amdgcn_readlane((int)v, 63);
}

// ---------------------------------------------------------------------------
// K1: wave-rolling Sobel (unchanged from round 3 — proven, not yet the top
// bottleneck). One wave owns a 64x32 strip; rows roll through registers;
// ballot IS the bitmap word; one global atomic per wave.
// ---------------------------------------------------------------------------
__global__ __launch_bounds__(256) void edge_mask_kernel(
    const float* __restrict__ mo, const float* __restrict__ lb,
    unsigned long long* __restrict__ bitmap, unsigned int* __restrict__ counts) {
  const int m = blockIdx.y;
  const int which = m & 1;
  const float* __restrict__ src = (which ? lb : mo) + (size_t)(m >> 1) * NPIX;
  const int l = threadIdx.x & 63;
  const int wi = blockIdx.x * 4 + (threadIdx.x >> 6);  // [0,128)
  const int cs = wi & 7;        // column strip
  const int seg = wi >> 3;      // row segment
  const int y0 = seg * 32;
  const int X = cs * 64 + l;
  const int hcol = (l == 0) ? X - 1 : ((l == 63) ? X + 1 : -1);

  auto sig = [&](float t) { return which ? t : 1.f / (1.f + expf(-t)); };
  auto ldmain = [&](int row) -> float {
    return ((unsigned)row < 512u) ? sig(src[row * 512 + X]) : 0.f;
  };
  auto ldhalo = [&](int row) -> float {
    return ((unsigned)row < 512u && (unsigned)hcol < 512u)
               ? sig(src[row * 512 + hcol]) : 0.f;
  };

  float a = ldmain(y0 - 1), ha = ldhalo(y0 - 1);
  float b = ldmain(y0),     hb = ldhalo(y0);
  unsigned int cnt = 0;

  for (int i = 0; i < 32; ++i) {
    const int y = y0 + i;
    float c = ldmain(y + 1), hc = ldhalo(y + 1);

    float aL = __shfl_up(a, 1);   if (l == 0)  aL = ha;
    float aR = __shfl_down(a, 1); if (l == 63) aR = ha;
    float bL = __shfl_up(b, 1);   if (l == 0)  bL = hb;
    float bR = __shfl_down(b, 1); if (l == 63) bR = hb;
    float cL = __shfl_up(c, 1);   if (l == 0)  cL = hc;
    float cR = __shfl_down(c, 1); if (l == 63) cR = hc;

    float ex = (aR - aL) + 2.f * (bR - bL) + (cR - cL);
    float ey = (cL + 2.f * c + cR) - (aL + 2.f * a + aR);
    float edge = sqrtf(ex * ex + ey * ey);
    bool bit = edge > 0.5f;

    unsigned long long ball = __ballot(bit);
    if (l == 0) {
      bitmap[(size_t)m * NWORDS + (size_t)y * 8 + cs] = ball;
      cnt += (unsigned int)__popcll(ball);
    }
    a = b; ha = hb; b = c; hb = hc;
  }
  if (l == 0 && cnt) atomicAdd(&counts[m], cnt);
}

// ---------------------------------------------------------------------------
// K2a: grid-wide candidate collection (unchanged).
// ---------------------------------------------------------------------------
__global__ __launch_bounds__(256) void collect_kernel(
    const unsigned long long* __restrict__ bitmap,
    const unsigned int* __restrict__ counts,
    unsigned long long* __restrict__ cand, unsigned int* __restrict__ gcnt) {
  const int m = blockIdx.y;
  const int tid = threadIdx.x;
  const int w = blockIdx.x * 256 + tid;

  __shared__ unsigned long long lbuf[LCAP];
  __shared__ unsigned int lcnt;
  __shared__ unsigned int lbase;
  if (tid == 0) lcnt = 0;
  __syncthreads();

  const unsigned int N = counts[m];
  if (N) {
    const uint32_t mt = thr_from_N(N);
    uint32_t k0, k1;
    map_key(m, k0, k1);
    unsigned long long word = bitmap[(size_t)m * NWORDS + w];
    while (word) {
      int bpos = __builtin_ctzll(word);
      word &= word - 1;
      uint32_t p = ((uint32_t)w << 6) + (uint32_t)bpos;
      uint32_t sc = score23(k0, k1, p);
      if (sc >= mt) {
        unsigned int pos = atomicAdd(&lcnt, 1u);
        if (pos < LCAP)
          lbuf[pos] = ((unsigned long long)sc << 32) | (uint32_t)(~p);
      }
    }
  }
  __syncthreads();
  unsigned int c = lcnt < LCAP ? lcnt : LCAP;
  if (tid == 0)
    lbase = atomicAdd(&gcnt[m], lcnt + (lcnt > LCAP ? 0x1000000u : 0u));
  __syncthreads();
  for (unsigned int i = tid; i < c; i += 256) {
    unsigned int pos = lbase + i;
    if (pos < CAP) cand[(size_t)m * CAP + pos] = lbuf[i];
  }
}

// ---------------------------------------------------------------------------
// K2b: radix-SELECT (not sort — MST weight is invariant to point order and
// start vertex, only the top-`need` SET matters). Distinct u64 keys < 2^56:
// 7 levels of 8-bit digits find the exact need-th largest key T, then emit
// all keys >= T (exactly `need` of them), unordered, as packed (row<<16|col).
// Fallback exact rescan if collection overflowed/short.
// ---------------------------------------------------------------------------
__global__ __launch_bounds__(256) void select_kernel(
    const unsigned long long* __restrict__ bitmap,
    const unsigned int* __restrict__ counts,
    const unsigned long long* __restrict__ cand,
    const unsigned int* __restrict__ gcnt,
    uint32_t* __restrict__ pts, unsigned int* __restrict__ nsel) {
  const int m = blockIdx.x;
  const int tid = threadIdx.x;
  __shared__ unsigned long long buf[CAP];
  __shared__ unsigned int hist[256];
  __shared__ unsigned int s_tot, s_cnt, s_b, s_rank;

  const unsigned int N = counts[m];
  if (N == 0) { if (tid == 0) nsel[m] = 0; return; }
  const unsigned int need = N < NPTS ? N : NPTS;

  unsigned int c;
  const unsigned int g = gcnt[m];
  if (g >= need && g <= CAP) {
    c = g;
    for (unsigned int i = tid; i < c; i += 256)
      buf[i] = cand[(size_t)m * CAP + i];
    __syncthreads();
  } else {
    // fallback: exact iterative rescan of the bitmap
    uint32_t k0, k1;
    map_key(m, k0, k1);
    const unsigned long long* __restrict__ wmap = bitmap + (size_t)m * NWORDS;
    unsigned int mt = 0, cnt = 0;
    double target = TARGET;
    for (int iter = 0; iter < 16; ++iter) {
      mt = ((double)N > target)
               ? (unsigned int)(8388608.0 * (1.0 - target / (double)N))
               : 0u;
      if (tid == 0) s_tot = 0;
      __syncthreads();
      unsigned int lc = 0;
      for (int w = tid; w < NWORDS; w += 256) {
        unsigned long long word = wmap[w];
        while (word) {
          int bpos = __builtin_ctzll(word);
          word &= word - 1;
          uint32_t p = ((uint32_t)w << 6) + (uint32_t)bpos;
          lc += (score23(k0, k1, p) >= mt) ? 1u : 0u;
        }
      }
      if (lc) atomicAdd(&s_tot, lc);
      __syncthreads();
      cnt = s_tot;
      __syncthreads();
      if (cnt >= need && cnt <= CAP) break;
      if (cnt < need) target *= 3.0; else target *= 0.5;
    }
    if (tid == 0) s_cnt = 0;
    __syncthreads();
    for (int w = tid; w < NWORDS; w += 256) {
      unsigned long long word = wmap[w];
      while (word) {
        int bpos = __builtin_ctzll(word);
        word &= word - 1;
        uint32_t p = ((uint32_t)w << 6) + (uint32_t)bpos;
        uint32_t sc = score23(k0, k1, p);
        if (sc >= mt) {
          unsigned int pos = atomicAdd(&s_cnt, 1u);
          if (pos < CAP)
            buf[pos] = ((unsigned long long)sc << 32) | (uint32_t)(~p);
        }
      }
    }
    __syncthreads();
    c = s_cnt < CAP ? s_cnt : CAP;
    __syncthreads();
  }

  unsigned long long T = 0ull;
  if (c > need) {
    unsigned int rank = need;
    unsigned long long prefix = 0ull;
    for (int sh = 48; sh >= 0; sh -= 8) {
      hist[tid] = 0;
      __syncthreads();
      for (unsigned int i = tid; i < c; i += 256) {
        unsigned long long k = buf[i];
        if ((k >> (sh + 8)) == (prefix >> (sh + 8)))
          atomicAdd(&hist[(unsigned int)(k >> sh) & 255u], 1u);
      }
      __syncthreads();
      if (tid < 64) {
        unsigned int h0 = hist[4 * tid], h1 = hist[4 * tid + 1];
        unsigned int h2 = hist[4 * tid + 2], h3 = hist[4 * tid + 3];
        unsigned int gsum = h0 + h1 + h2 + h3;
        unsigned int s = gsum;
#pragma unroll
        for (int off = 1; off < 64; off <<= 1) {
          unsigned int o = __shfl_down(s, off, 64);
          s += (tid + off < 64) ? o : 0u;
        }
        unsigned int above = s - gsum;  // strictly higher digits
        unsigned int S3 = above, S2 = S3 + h3, S1 = S2 + h2, S0 = S1 + h1;
        if (S3 < rank && rank <= S3 + h3) { s_b = 4 * tid + 3; s_rank = rank - S3; }
        if (S2 < rank && rank <= S2 + h2) { s_b = 4 * tid + 2; s_rank = rank - S2; }
        if (S1 < rank && rank <= S1 + h1) { s_b = 4 * tid + 1; s_rank = rank - S1; }
        if (S0 < rank && rank <= S0 + h0) { s_b = 4 * tid + 0; s_rank = rank - S0; }
      }
      __syncthreads();
      prefix |= ((unsigned long long)s_b) << sh;
      rank = s_rank;
    }
    T = prefix;  // exact need-th largest key
  }

  if (tid == 0) s_cnt = 0;
  __syncthreads();
  for (unsigned int i = tid; i < c; i += 256) {
    unsigned long long k = buf[i];
    if (k >= T) {
      unsigned int pos = atomicAdd(&s_cnt, 1u);
      if (pos < NPTS) {
        uint32_t p = ~(uint32_t)k;
        pts[(size_t)m * NPTS + pos] = ((p >> 9) << 16) | (p & 511u);
      }
    }
  }
  __syncthreads();
  if (tid == 0) nsel[m] = s_cnt < need ? s_cnt : need;
}

// ---------------------------------------------------------------------------
// K3: Prim MST, one wave/map, all-integer d^2 (exact: coords<512 => d2<2^19,
// f32-exact too). Frontier key = (d2<<9 | id) in ONE u32; argmin via DPP
// reduction + readlane (no LDS, no barriers, no bpermute). In-tree/invalid
// slots pinned at 0xFFFFFFFF. Start vertex arbitrary: MST weight multiset is
// start- and order-invariant; f32 sum reorder error << tolerance.
// ---------------------------------------------------------------------------
__global__ __launch_bounds__(64) void mst_kernel(
    const uint32_t* __restrict__ pts, const unsigned int* __restrict__ nsel,
    float* __restrict__ tps) {
  const int m = blockIdx.x;
  const int l = threadIdx.x;
  const int n = (int)nsel[m];
  if (n <= 1) { if (l == 0) tps[m] = 0.f; return; }

  uint32_t pk[5], key[5];
  int px[5], py[5];
#pragma unroll
  for (int k = 0; k < 5; ++k) {
    int id = k * 64 + l;
    pk[k] = (id < n) ? pts[(size_t)m * NPTS + id] : 0u;
  }
  const uint32_t p0 = (uint32_t)__builtin_amdgcn_readlane((int)pk[0], 0);
  const int x0 = (int)(p0 >> 16), y0 = (int)(p0 & 0xFFFFu);
#pragma unroll
  for (int k = 0; k < 5; ++k) {
    int id = k * 64 + l;
    px[k] = (int)(pk[k] >> 16);
    py[k] = (int)(pk[k] & 0xFFFFu);
    if (id > 0 && id < n) {
      int dx = px[k] - x0, dy = py[k] - y0;
      key[k] = ((uint32_t)(dx * dx + dy * dy) << 9) | (uint32_t)id;
    } else {
      key[k] = 0xFFFFFFFFu;
    }
  }

  float tp = 0.f;
  for (int it = 0; it < n - 1; ++it) {
    uint32_t best = umin32(umin32(umin32(key[0], key[1]),
                                  umin32(key[2], key[3])), key[4]);
    best = wave_min_bcast(best);  // uniform across wave
    tp += (float)(best >> 9);     // exact: d2 < 2^19
    const int j = (int)(best & 511u);
    const int ko = j >> 6, lo = j & 63;
    uint32_t cp = pk[0];
#pragma unroll
    for (int k = 1; k < 5; ++k) cp = (ko == k) ? pk[k] : cp;
    const uint32_t pj = (uint32_t)__builtin_amdgcn_readlane((int)cp, lo);
    const int jx = (int)(pj >> 16), jy = (int)(pj & 0xFFFFu);
#pragma unroll
    for (int k = 0; k < 5; ++k) {
      int dx = px[k] - jx, dy = py[k] - jy;
      uint32_t nk = ((uint32_t)(dx * dx + dy * dy) << 9) |
                    (uint32_t)(k * 64 + l);
      uint32_t upd = (key[k] == 0xFFFFFFFFu) ? 0xFFFFFFFFu : umin32(key[k], nk);
      key[k] = (k == ko && l == lo) ? 0xFFFFFFFFu : upd;
    }
  }
  if (l == 0) tps[m] = tp;
}

// ---------------------------------------------------------------------------
// K4: loss = 1e-5 * sum_b |tp_mask - tp_pred| / 32
// ---------------------------------------------------------------------------
__global__ void finalize_kernel(const float* __restrict__ tps,
                                float* __restrict__ out) {
  const int tid = threadIdx.x;
  float v = 0.f;
  if (tid < 32) v = fabsf(tps[2 * tid + 1] - tps[2 * tid]);
#pragma unroll
  for (int off = 32; off > 0; off >>= 1) v += __shfl_xor(v, off, 64);
  if (tid == 0) out[0] = 1e-5f * v / 32.f;
}

// ---------------------------------------------------------------------------
extern "C" void kernel_launch(void* const* d_in, const int* in_sizes, int n_in,
                              void* d_out, int out_size, void* d_ws,
                              size_t ws_size, hipStream_t stream) {
  const float* mo = (const float*)d_in[0];
  const float* lb = (const float*)d_in[1];
  float* out = (float*)d_out;
  char* ws = (char*)d_ws;

  // ws layout (~3.2 MB):
  unsigned long long* bitmap = (unsigned long long*)ws;            // 2 MB
  unsigned int* counts = (unsigned int*)(ws + 2097152);            // 256 B
  unsigned int* gcnt   = (unsigned int*)(ws + 2097408);            // 256 B
  unsigned int* nsel   = (unsigned int*)(ws + 2097664);            // 256 B
  float* tps           = (float*)(ws + 2097920);                   // 256 B
  uint32_t* pts        = (uint32_t*)(ws + 2098176);                // 75 KB
  unsigned long long* cand = (unsigned long long*)(ws + 2251776);  // 1 MB

  hipMemsetAsync(counts, 0, 512, stream);  // counts + gcnt
  edge_mask_kernel<<<dim3(32, 64), 256, 0, stream>>>(mo, lb, bitmap, counts);
  collect_kernel<<<dim3(16, 64), 256, 0, stream>>>(bitmap, counts, cand, gcnt);
  select_kernel<<<NMAPS, 256, 0, stream>>>(bitmap, counts, cand, gcnt, pts, nsel);
  mst_kernel<<<NMAPS, 64, 0, stream>>>(pts, nsel, tps);
  finalize_kernel<<<1, 64, 0, stream>>>(tps, out);
}

// Round 5
// 269.107 us; speedup vs baseline: 4.0751x; 1.0481x over previous
//
#include <hip/hip_runtime.h>
#include <cstdint>
#include <cstddef>

#define NPIX (512 * 512)
#define NMAPS 64
#define NPTS 300
#define CAP 2048          // global candidate cap per map (mean ~700)
#define LCAP 640          // per-block LDS candidate cap (mean ~44)
#define NWORDS 4096       // 262144 bits / 64
#define TARGET 700.0      // expected survivor count per map

__device__ __forceinline__ uint32_t umin32(uint32_t a, uint32_t b) {
  return a < b ? a : b;
}

// ---------------------------------------------------------------------------
// Threefry-2x32, 20 rounds (exactly JAX's formulation).
// ---------------------------------------------------------------------------
__device__ __forceinline__ void tf2x32(uint32_t k0, uint32_t k1,
                                       uint32_t x0, uint32_t x1,
                                       uint32_t& o0, uint32_t& o1) {
  uint32_t ks2 = k0 ^ k1 ^ 0x1BD11BDAu;
#define TFR(r) { x0 += x1; x1 = (x1 << (r)) | (x1 >> (32 - (r))); x1 ^= x0; }
  x0 += k0; x1 += k1;
  TFR(13) TFR(15) TFR(26) TFR(6)
  x0 += k1; x1 += ks2 + 1u;
  TFR(17) TFR(29) TFR(16) TFR(24)
  x0 += ks2; x1 += k0 + 2u;
  TFR(13) TFR(15) TFR(26) TFR(6)
  x0 += k0; x1 += k1 + 3u;
  TFR(17) TFR(29) TFR(16) TFR(24)
  x0 += k1; x1 += ks2 + 4u;
  TFR(13) TFR(15) TFR(26) TFR(6)
  x0 += ks2; x1 += k0 + 5u;
#undef TFR
  o0 = x0; o1 = x1;
}

// partitionable threefry: bits at flat pixel p = o0^o1 of block (0,p);
// uniform f32 keeps mantissa bits>>9 (monotone) — compare as 23-bit ints.
__device__ __forceinline__ uint32_t score23(uint32_t k0, uint32_t k1, uint32_t p) {
  uint32_t a, b;
  tf2x32(k0, k1, 0u, p, a, b);
  return (a ^ b) >> 9;
}

__device__ __forceinline__ void map_key(int m, uint32_t& k0, uint32_t& k1) {
  tf2x32(0u, 42u, 0u, (uint32_t)m, k0, k1);  // split(key(42),64)[m]
}

__device__ __forceinline__ uint32_t thr_from_N(unsigned int N) {
  return ((double)N > TARGET)
             ? (uint32_t)(8388608.0 * (1.0 - TARGET / (double)N))
             : 0u;
}

// ---------------------------------------------------------------------------
// DPP wave-64 min reduction (4x row_shr + row_bcast15 + row_bcast31, result
// in lane 63) then scalar broadcast. bound_ctrl=false => invalid lanes keep
// old (=v) which is the min identity.
// ---------------------------------------------------------------------------
__device__ __forceinline__ uint32_t wave_min_bcast(uint32_t v) {
#define DPPMIN(ctrl)                                                         \
  v = umin32(v, (uint32_t)__builtin_amdgcn_update_dpp(                       \
                    (int)v, (int)v, (ctrl), 0xF, 0xF, false));
  DPPMIN(0x111)  // row_shr:1
  DPPMIN(0x112)  // row_shr:2
  DPPMIN(0x114)  // row_shr:4
  DPPMIN(0x118)  // row_shr:8
  DPPMIN(0x142)  // row_bcast:15
  DPPMIN(0x143)  // row_bcast:31
#undef DPPMIN
  return (uint32_t)__builtin_amdgcn_readlane((int)v, 63);
}

// ---------------------------------------------------------------------------
// K1: wave-rolling Sobel. One wave owns a 64x32 strip; rows roll through
// registers; ballot IS the bitmap word. ZERO atomics now: each wave stores
// its private count to a disjoint slot (round-2/4 lesson: shared-cache-line
// RMW atomics across XCDs cost ~18+ ns each, 8192 of them ~ 150 us).
// ---------------------------------------------------------------------------
__global__ __launch_bounds__(256) void edge_mask_kernel(
    const float* __restrict__ mo, const float* __restrict__ lb,
    unsigned long long* __restrict__ bitmap, unsigned int* __restrict__ wcnts) {
  const int m = blockIdx.y;
  const int which = m & 1;
  const float* __restrict__ src = (which ? lb : mo) + (size_t)(m >> 1) * NPIX;
  const int l = threadIdx.x & 63;
  const int wi = blockIdx.x * 4 + (threadIdx.x >> 6);  // [0,128)
  const int cs = wi & 7;        // column strip
  const int seg = wi >> 3;      // row segment
  const int y0 = seg * 32;
  const int X = cs * 64 + l;
  const int hcol = (l == 0) ? X - 1 : ((l == 63) ? X + 1 : -1);

  auto sig = [&](float t) { return which ? t : 1.f / (1.f + expf(-t)); };
  auto ldmain = [&](int row) -> float {
    return ((unsigned)row < 512u) ? sig(src[row * 512 + X]) : 0.f;
  };
  auto ldhalo = [&](int row) -> float {
    return ((unsigned)row < 512u && (unsigned)hcol < 512u)
               ? sig(src[row * 512 + hcol]) : 0.f;
  };

  float a = ldmain(y0 - 1), ha = ldhalo(y0 - 1);
  float b = ldmain(y0),     hb = ldhalo(y0);
  unsigned int cnt = 0;

  for (int i = 0; i < 32; ++i) {
    const int y = y0 + i;
    float c = ldmain(y + 1), hc = ldhalo(y + 1);

    float aL = __shfl_up(a, 1);   if (l == 0)  aL = ha;
    float aR = __shfl_down(a, 1); if (l == 63) aR = ha;
    float bL = __shfl_up(b, 1);   if (l == 0)  bL = hb;
    float bR = __shfl_down(b, 1); if (l == 63) bR = hb;
    float cL = __shfl_up(c, 1);   if (l == 0)  cL = hc;
    float cR = __shfl_down(c, 1); if (l == 63) cR = hc;

    float ex = (aR - aL) + 2.f * (bR - bL) + (cR - cL);
    float ey = (cL + 2.f * c + cR) - (aL + 2.f * a + aR);
    float edge = sqrtf(ex * ex + ey * ey);
    bool bit = edge > 0.5f;

    unsigned long long ball = __ballot(bit);
    if (l == 0) {
      bitmap[(size_t)m * NWORDS + (size_t)y * 8 + cs] = ball;
      cnt += (unsigned int)__popcll(ball);
    }
    a = b; ha = hb; b = c; hb = hc;
  }
  if (l == 0) wcnts[m * 128 + wi] = cnt;
}

// ---------------------------------------------------------------------------
// K1b: counts[m] = sum of 128 per-wave counts. One wave per map, no atomics.
// ---------------------------------------------------------------------------
__global__ __launch_bounds__(64) void reduce_counts_kernel(
    const unsigned int* __restrict__ wcnts, unsigned int* __restrict__ counts) {
  const int m = blockIdx.x;
  const int l = threadIdx.x;
  unsigned int v = wcnts[m * 128 + l] + wcnts[m * 128 + 64 + l];
#pragma unroll
  for (int off = 32; off > 0; off >>= 1) v += __shfl_xor(v, off, 64);
  if (l == 0) counts[m] = v;
}

// ---------------------------------------------------------------------------
// K2a: grid-wide candidate collection (unchanged).
// ---------------------------------------------------------------------------
__global__ __launch_bounds__(256) void collect_kernel(
    const unsigned long long* __restrict__ bitmap,
    const unsigned int* __restrict__ counts,
    unsigned long long* __restrict__ cand, unsigned int* __restrict__ gcnt) {
  const int m = blockIdx.y;
  const int tid = threadIdx.x;
  const int w = blockIdx.x * 256 + tid;

  __shared__ unsigned long long lbuf[LCAP];
  __shared__ unsigned int lcnt;
  __shared__ unsigned int lbase;
  if (tid == 0) lcnt = 0;
  __syncthreads();

  const unsigned int N = counts[m];
  if (N) {
    const uint32_t mt = thr_from_N(N);
    uint32_t k0, k1;
    map_key(m, k0, k1);
    unsigned long long word = bitmap[(size_t)m * NWORDS + w];
    while (word) {
      int bpos = __builtin_ctzll(word);
      word &= word - 1;
      uint32_t p = ((uint32_t)w << 6) + (uint32_t)bpos;
      uint32_t sc = score23(k0, k1, p);
      if (sc >= mt) {
        unsigned int pos = atomicAdd(&lcnt, 1u);
        if (pos < LCAP)
          lbuf[pos] = ((unsigned long long)sc << 32) | (uint32_t)(~p);
      }
    }
  }
  __syncthreads();
  unsigned int c = lcnt < LCAP ? lcnt : LCAP;
  if (tid == 0)
    lbase = atomicAdd(&gcnt[m], lcnt + (lcnt > LCAP ? 0x1000000u : 0u));
  __syncthreads();
  for (unsigned int i = tid; i < c; i += 256) {
    unsigned int pos = lbase + i;
    if (pos < CAP) cand[(size_t)m * CAP + pos] = lbuf[i];
  }
}

// ---------------------------------------------------------------------------
// K2b: radix-SELECT (unchanged; only the top-`need` SET matters).
// ---------------------------------------------------------------------------
__global__ __launch_bounds__(256) void select_kernel(
    const unsigned long long* __restrict__ bitmap,
    const unsigned int* __restrict__ counts,
    const unsigned long long* __restrict__ cand,
    const unsigned int* __restrict__ gcnt,
    uint32_t* __restrict__ pts, unsigned int* __restrict__ nsel) {
  const int m = blockIdx.x;
  const int tid = threadIdx.x;
  __shared__ unsigned long long buf[CAP];
  __shared__ unsigned int hist[256];
  __shared__ unsigned int s_tot, s_cnt, s_b, s_rank;

  const unsigned int N = counts[m];
  if (N == 0) { if (tid == 0) nsel[m] = 0; return; }
  const unsigned int need = N < NPTS ? N : NPTS;

  unsigned int c;
  const unsigned int g = gcnt[m];
  if (g >= need && g <= CAP) {
    c = g;
    for (unsigned int i = tid; i < c; i += 256)
      buf[i] = cand[(size_t)m * CAP + i];
    __syncthreads();
  } else {
    // fallback: exact iterative rescan of the bitmap
    uint32_t k0, k1;
    map_key(m, k0, k1);
    const unsigned long long* __restrict__ wmap = bitmap + (size_t)m * NWORDS;
    unsigned int mt = 0, cnt = 0;
    double target = TARGET;
    for (int iter = 0; iter < 16; ++iter) {
      mt = ((double)N > target)
               ? (unsigned int)(8388608.0 * (1.0 - target / (double)N))
               : 0u;
      if (tid == 0) s_tot = 0;
      __syncthreads();
      unsigned int lc = 0;
      for (int w = tid; w < NWORDS; w += 256) {
        unsigned long long word = wmap[w];
        while (word) {
          int bpos = __builtin_ctzll(word);
          word &= word - 1;
          uint32_t p = ((uint32_t)w << 6) + (uint32_t)bpos;
          lc += (score23(k0, k1, p) >= mt) ? 1u : 0u;
        }
      }
      if (lc) atomicAdd(&s_tot, lc);
      __syncthreads();
      cnt = s_tot;
      __syncthreads();
      if (cnt >= need && cnt <= CAP) break;
      if (cnt < need) target *= 3.0; else target *= 0.5;
    }
    if (tid == 0) s_cnt = 0;
    __syncthreads();
    for (int w = tid; w < NWORDS; w += 256) {
      unsigned long long word = wmap[w];
      while (word) {
        int bpos = __builtin_ctzll(word);
        word &= word - 1;
        uint32_t p = ((uint32_t)w << 6) + (uint32_t)bpos;
        uint32_t sc = score23(k0, k1, p);
        if (sc >= mt) {
          unsigned int pos = atomicAdd(&s_cnt, 1u);
          if (pos < CAP)
            buf[pos] = ((unsigned long long)sc << 32) | (uint32_t)(~p);
        }
      }
    }
    __syncthreads();
    c = s_cnt < CAP ? s_cnt : CAP;
    __syncthreads();
  }

  unsigned long long T = 0ull;
  if (c > need) {
    unsigned int rank = need;
    unsigned long long prefix = 0ull;
    for (int sh = 48; sh >= 0; sh -= 8) {
      hist[tid] = 0;
      __syncthreads();
      for (unsigned int i = tid; i < c; i += 256) {
        unsigned long long k = buf[i];
        if ((k >> (sh + 8)) == (prefix >> (sh + 8)))
          atomicAdd(&hist[(unsigned int)(k >> sh) & 255u], 1u);
      }
      __syncthreads();
      if (tid < 64) {
        unsigned int h0 = hist[4 * tid], h1 = hist[4 * tid + 1];
        unsigned int h2 = hist[4 * tid + 2], h3 = hist[4 * tid + 3];
        unsigned int gsum = h0 + h1 + h2 + h3;
        unsigned int s = gsum;
#pragma unroll
        for (int off = 1; off < 64; off <<= 1) {
          unsigned int o = __shfl_down(s, off, 64);
          s += (tid + off < 64) ? o : 0u;
        }
        unsigned int above = s - gsum;  // strictly higher digits
        unsigned int S3 = above, S2 = S3 + h3, S1 = S2 + h2, S0 = S1 + h1;
        if (S3 < rank && rank <= S3 + h3) { s_b = 4 * tid + 3; s_rank = rank - S3; }
        if (S2 < rank && rank <= S2 + h2) { s_b = 4 * tid + 2; s_rank = rank - S2; }
        if (S1 < rank && rank <= S1 + h1) { s_b = 4 * tid + 1; s_rank = rank - S1; }
        if (S0 < rank && rank <= S0 + h0) { s_b = 4 * tid + 0; s_rank = rank - S0; }
      }
      __syncthreads();
      prefix |= ((unsigned long long)s_b) << sh;
      rank = s_rank;
    }
    T = prefix;  // exact need-th largest key
  }

  if (tid == 0) s_cnt = 0;
  __syncthreads();
  for (unsigned int i = tid; i < c; i += 256) {
    unsigned long long k = buf[i];
    if (k >= T) {
      unsigned int pos = atomicAdd(&s_cnt, 1u);
      if (pos < NPTS) {
        uint32_t p = ~(uint32_t)k;
        pts[(size_t)m * NPTS + pos] = ((p >> 9) << 16) | (p & 511u);
      }
    }
  }
  __syncthreads();
  if (tid == 0) nsel[m] = s_cnt < need ? s_cnt : need;
}

// ---------------------------------------------------------------------------
// K3: Prim MST, one wave/map, all-integer d^2, DPP argmin, zero barriers.
// __launch_bounds__(64, 1): only 64 blocks exist; let the compiler use all
// the VGPRs it wants — round-4's VGPR_Count=12 proved it was spilling the
// 25 live values to scratch (~680 cyc/iter instead of ~150).
// ---------------------------------------------------------------------------
__global__ __launch_bounds__(64, 1) void mst_kernel(
    const uint32_t* __restrict__ pts, const unsigned int* __restrict__ nsel,
    float* __restrict__ tps) {
  const int m = blockIdx.x;
  const int l = threadIdx.x;
  const int n = (int)nsel[m];
  if (n <= 1) { if (l == 0) tps[m] = 0.f; return; }

  uint32_t pk[5], key[5];
  int px[5], py[5];
#pragma unroll
  for (int k = 0; k < 5; ++k) {
    int id = k * 64 + l;
    pk[k] = (id < n) ? pts[(size_t)m * NPTS + id] : 0u;
  }
  const uint32_t p0 = (uint32_t)__builtin_amdgcn_readlane((int)pk[0], 0);
  const int x0 = (int)(p0 >> 16), y0 = (int)(p0 & 0xFFFFu);
#pragma unroll
  for (int k = 0; k < 5; ++k) {
    int id = k * 64 + l;
    px[k] = (int)(pk[k] >> 16);
    py[k] = (int)(pk[k] & 0xFFFFu);
    if (id > 0 && id < n) {
      int dx = px[k] - x0, dy = py[k] - y0;
      key[k] = ((uint32_t)(dx * dx + dy * dy) << 9) | (uint32_t)id;
    } else {
      key[k] = 0xFFFFFFFFu;
    }
  }

  float tp = 0.f;
  for (int it = 0; it < n - 1; ++it) {
    uint32_t best = umin32(umin32(umin32(key[0], key[1]),
                                  umin32(key[2], key[3])), key[4]);
    best = wave_min_bcast(best);  // uniform across wave
    tp += (float)(best >> 9);     // exact: d2 < 2^19
    const int j = (int)(best & 511u);
    const int ko = j >> 6, lo = j & 63;
    uint32_t cp = pk[0];
#pragma unroll
    for (int k = 1; k < 5; ++k) cp = (ko == k) ? pk[k] : cp;
    const uint32_t pj = (uint32_t)__builtin_amdgcn_readlane((int)cp, lo);
    const int jx = (int)(pj >> 16), jy = (int)(pj & 0xFFFFu);
#pragma unroll
    for (int k = 0; k < 5; ++k) {
      int dx = px[k] - jx, dy = py[k] - jy;
      uint32_t nk = ((uint32_t)(dx * dx + dy * dy) << 9) |
                    (uint32_t)(k * 64 + l);
      uint32_t upd = (key[k] == 0xFFFFFFFFu) ? 0xFFFFFFFFu : umin32(key[k], nk);
      key[k] = (k == ko && l == lo) ? 0xFFFFFFFFu : upd;
    }
  }
  if (l == 0) tps[m] = tp;
}

// ---------------------------------------------------------------------------
// K4: loss = 1e-5 * sum_b |tp_mask - tp_pred| / 32
// ---------------------------------------------------------------------------
__global__ void finalize_kernel(const float* __restrict__ tps,
                                float* __restrict__ out) {
  const int tid = threadIdx.x;
  float v = 0.f;
  if (tid < 32) v = fabsf(tps[2 * tid + 1] - tps[2 * tid]);
#pragma unroll
  for (int off = 32; off > 0; off >>= 1) v += __shfl_xor(v, off, 64);
  if (tid == 0) out[0] = 1e-5f * v / 32.f;
}

// ---------------------------------------------------------------------------
extern "C" void kernel_launch(void* const* d_in, const int* in_sizes, int n_in,
                              void* d_out, int out_size, void* d_ws,
                              size_t ws_size, hipStream_t stream) {
  const float* mo = (const float*)d_in[0];
  const float* lb = (const float*)d_in[1];
  float* out = (float*)d_out;
  char* ws = (char*)d_ws;

  // ws layout (~3.4 MB):
  unsigned long long* bitmap = (unsigned long long*)ws;            // 2 MB
  unsigned int* counts = (unsigned int*)(ws + 2097152);            // 256 B
  unsigned int* gcnt   = (unsigned int*)(ws + 2097408);            // 256 B
  unsigned int* nsel   = (unsigned int*)(ws + 2097664);            // 256 B
  float* tps           = (float*)(ws + 2097920);                   // 256 B
  uint32_t* pts        = (uint32_t*)(ws + 2098176);                // 75 KB
  unsigned long long* cand = (unsigned long long*)(ws + 2251776);  // 1 MB
  unsigned int* wcnts  = (unsigned int*)(ws + 3300352);            // 32 KB

  hipMemsetAsync(gcnt, 0, 256, stream);  // only gcnt needs zeroing now
  edge_mask_kernel<<<dim3(32, 64), 256, 0, stream>>>(mo, lb, bitmap, wcnts);
  reduce_counts_kernel<<<NMAPS, 64, 0, stream>>>(wcnts, counts);
  collect_kernel<<<dim3(16, 64), 256, 0, stream>>>(bitmap, counts, cand, gcnt);
  select_kernel<<<NMAPS, 256, 0, stream>>>(bitmap, counts, cand, gcnt, pts, nsel);
  mst_kernel<<<NMAPS, 64, 0, stream>>>(pts, nsel, tps);
  finalize_kernel<<<1, 64, 0, stream>>>(tps, out);
}